// Round 1
// baseline (756.401 us; speedup 1.0000x reference)
//
#include <hip/hip_runtime.h>
#include <hip/hip_bf16.h>

// Problem: S=1024, B=512, F=128, H=3
//   xp[s,b,h] = dot(x[s,b,:], W_ih[h,:]) + b_ih[h] + b_hh[h]   (bias folded)
//   h_t = tanh(xp[t] + W_hh @ h_{t-1})
//   delta[s,b] = signal[argmax_h(h[s,b,:] + gumbel[s,b,:])]   (hard gumbel fwd)
//   out = [delta (S*B floats), h_T (B*H floats)]

#define S_DIM 1024
#define B_DIM 512
#define F_DIM 128
#define H_DIM 3

// ---------------- Kernel 1: input projection (memory-bound, 256 MB read) ----
// One thread per (s,b) row. Each lane streams its own 512B row as float4;
// W_ih indices are wave-uniform -> scalarized to s_load (K$-resident).
__global__ __launch_bounds__(256) void k_inproj(
    const float* __restrict__ x,      // (S,B,F)
    const float* __restrict__ W,      // (H,F) = (3,128)
    const float* __restrict__ b_ih,   // (3)
    const float* __restrict__ b_hh,   // (3)
    float* __restrict__ xp)           // (S*B, 4) padded
{
    int row = blockIdx.x * 256 + threadIdx.x;        // 0 .. S*B-1
    const float4* xr = (const float4*)(x + (size_t)row * F_DIM);
    const float4* W0 = (const float4*)(W);
    const float4* W1 = (const float4*)(W + F_DIM);
    const float4* W2 = (const float4*)(W + 2 * F_DIM);

    float a0 = 0.f, a1 = 0.f, a2 = 0.f;
#pragma unroll 8
    for (int i = 0; i < F_DIM / 4; ++i) {
        float4 v  = xr[i];
        float4 w0 = W0[i];   // uniform -> s_load
        float4 w1 = W1[i];
        float4 w2 = W2[i];
        a0 += v.x * w0.x + v.y * w0.y + v.z * w0.z + v.w * w0.w;
        a1 += v.x * w1.x + v.y * w1.y + v.z * w1.z + v.w * w1.w;
        a2 += v.x * w2.x + v.y * w2.y + v.z * w2.z + v.w * w2.w;
    }
    float4 o;
    o.x = a0 + b_ih[0] + b_hh[0];
    o.y = a1 + b_ih[1] + b_hh[1];
    o.z = a2 + b_ih[2] + b_hh[2];
    o.w = 0.f;
    ((float4*)xp)[row] = o;
}

// ---------------- Kernel 2: sequential scan + gumbel-hard (latency-bound) ---
__device__ __forceinline__ float tanh_fast(float xv) {
    // tanh(x) = 1 - 2/(e^{2x}+1); exact at +-inf saturation.
    float e = __expf(2.0f * xv);                 // v_exp_f32 path
    return 1.0f - 2.0f * __builtin_amdgcn_rcpf(e + 1.0f);
}

__global__ __launch_bounds__(64) void k_scan(
    const float* __restrict__ xp,      // (S*B, 4) padded, bias folded
    const float* __restrict__ gumbel,  // (S,B,3)
    const float* __restrict__ W_hh,    // (3,3)
    const float* __restrict__ signal,  // (3,1)
    float* __restrict__ out)           // [S*B delta] ++ [B*3 hidden]
{
    int b = blockIdx.x * 64 + threadIdx.x;   // 0..511

    // W_hh / signal are wave-uniform -> scalar loads.
    float w00 = W_hh[0], w01 = W_hh[1], w02 = W_hh[2];
    float w10 = W_hh[3], w11 = W_hh[4], w12 = W_hh[5];
    float w20 = W_hh[6], w21 = W_hh[7], w22 = W_hh[8];
    float s0 = signal[0], s1 = signal[1], s2 = signal[2];

    float h0 = 0.f, h1 = 0.f, h2 = 0.f;

    const float4* xp4 = (const float4*)xp;

    // 1-deep software prefetch: loads never depend on h.
    float4 xv = xp4[b];
    const float* g = gumbel + (size_t)b * 3;
    float g0 = g[0], g1 = g[1], g2 = g[2];

    for (int s = 0; s < S_DIM; ++s) {
        int sn = (s + 1 < S_DIM) ? (s + 1) : s;
        float4 xv_n = xp4[(size_t)sn * B_DIM + b];
        const float* gn = gumbel + ((size_t)sn * B_DIM + b) * 3;
        float g0n = gn[0], g1n = gn[1], g2n = gn[2];

        float a0 = xv.x + w00 * h0 + w01 * h1 + w02 * h2;
        float a1 = xv.y + w10 * h0 + w11 * h1 + w12 * h2;
        float a2 = xv.z + w20 * h0 + w21 * h1 + w22 * h2;
        h0 = tanh_fast(a0);
        h1 = tanh_fast(a1);
        h2 = tanh_fast(a2);

        float l0 = h0 + g0, l1 = h1 + g1, l2 = h2 + g2;
        // jnp.argmax first-max tie rule.
        float d = (l2 > l0 && l2 > l1) ? s2 : ((l1 > l0) ? s1 : s0);
        out[s * B_DIM + b] = d;

        xv = xv_n; g0 = g0n; g1 = g1n; g2 = g2n;
    }

    // hidden_state = h_T, shape (1,B,3), appended after delta.
    float* hid = out + (size_t)S_DIM * B_DIM + (size_t)b * 3;
    hid[0] = h0; hid[1] = h1; hid[2] = h2;
}

extern "C" void kernel_launch(void* const* d_in, const int* in_sizes, int n_in,
                              void* d_out, int out_size, void* d_ws, size_t ws_size,
                              hipStream_t stream) {
    const float* x      = (const float*)d_in[0];  // (S,B,F)
    const float* gumbel = (const float*)d_in[1];  // (S,B,H)
    const float* W_ih   = (const float*)d_in[2];  // (H,F)
    const float* W_hh   = (const float*)d_in[3];  // (H,H)
    const float* b_ih   = (const float*)d_in[4];  // (H)
    const float* b_hh   = (const float*)d_in[5];  // (H)
    const float* signal = (const float*)d_in[6];  // (H,1)

    float* xp = (float*)d_ws;                     // S*B*4 floats = 8 MB
    float* out = (float*)d_out;                   // 525824 floats

    k_inproj<<<(S_DIM * B_DIM) / 256, 256, 0, stream>>>(x, W_ih, b_ih, b_hh, xp);
    k_scan<<<B_DIM / 64, 64, 0, stream>>>(xp, gumbel, W_hh, signal, out);
}

// Round 3
// 480.539 us; speedup vs baseline: 1.5741x; 1.5741x over previous
//
#include <hip/hip_runtime.h>
#include <hip/hip_bf16.h>

// Problem: S=1024, B=512, F=128, H=3
//   xp[s,b,h] = dot(x[s,b,:], W_ih[h,:]) + b_ih[h] + b_hh[h]   (bias folded)
//   h_t = tanh(xp[t] + W_hh @ h_{t-1})
//   delta[s,b] = signal[argmax_h(h[s,b,:] + gumbel[s,b,:])]   (hard gumbel fwd)
//   out = [delta (S*B floats), h_T (B*3 floats)]

#define S_DIM 1024
#define B_DIM 512
#define F_DIM 128

// ---------------- Kernel 1: input projection + gumbel pack ------------------
// 32 lanes per row. Lane l loads float4 l of the row (wave = 2 rows x 512B
// contiguous per instruction => perfect coalescing, every byte of a line
// consumed by the instruction that pulls it). Dot with per-lane W chunk,
// butterfly-reduce over 32 lanes, write packed row:
//   xpk[row*8 + {0,1,2}] = a0,a1,a2 (+biases);  xpk[row*8 + {4,5,6}] = gumbel.
__global__ __launch_bounds__(256) void k_inproj(
    const float* __restrict__ x,       // (S,B,F)
    const float* __restrict__ gumbel,  // (S,B,3)
    const float* __restrict__ W,       // (3,128)
    const float* __restrict__ b_ih,    // (3)
    const float* __restrict__ b_hh,    // (3)
    float* __restrict__ xpk)           // (S*B, 8)
{
    int tid = blockIdx.x * 256 + threadIdx.x;
    int row = tid >> 5;                 // 0 .. S*B-1
    int l   = tid & 31;                 // float4 chunk within the row

    // Per-lane W chunks (1.5 KB total, L1-resident after first wave).
    float4 w0 = ((const float4*)(W))[l];
    float4 w1 = ((const float4*)(W + F_DIM))[l];
    float4 w2 = ((const float4*)(W + 2 * F_DIM))[l];

    float4 v = ((const float4*)x)[(size_t)row * 32 + l];

    float p0 = v.x * w0.x + v.y * w0.y + v.z * w0.z + v.w * w0.w;
    float p1 = v.x * w1.x + v.y * w1.y + v.z * w1.z + v.w * w1.w;
    float p2 = v.x * w2.x + v.y * w2.y + v.z * w2.z + v.w * w2.w;

    // Butterfly reduce across the 32-lane group (masks <=16 never cross the
    // 32-lane halves of the 64-wide wave).
#pragma unroll
    for (int m = 1; m <= 16; m <<= 1) {
        p0 += __shfl_xor(p0, m, 64);
        p1 += __shfl_xor(p1, m, 64);
        p2 += __shfl_xor(p2, m, 64);
    }

    if (l < 3) {
        float a = (l == 0) ? p0 : ((l == 1) ? p1 : p2);
        xpk[(size_t)row * 8 + l] = a + b_ih[l] + b_hh[l];
    } else if (l >= 4 && l < 7) {
        xpk[(size_t)row * 8 + l] = gumbel[(size_t)row * 3 + (l - 4)];
    }
}

// ---------------- Kernel 2: sequential scan, 16-deep prefetch ---------------
__device__ __forceinline__ float tanh_fast(float xv) {
    float e = __expf(2.0f * xv);
    return 1.0f - 2.0f * __builtin_amdgcn_rcpf(e + 1.0f);
}

#define U_PF 16   // prefetch depth; 2 loads/step * 16 = 32 outstanding < 63

__global__ __launch_bounds__(64) void k_scan(
    const float* __restrict__ xpk,     // (S*B, 8) packed: xp | gumbel
    const float* __restrict__ W_hh,    // (3,3)
    const float* __restrict__ signal,  // (3,1)
    float* __restrict__ out)           // [S*B delta] ++ [B*3 hidden]
{
    int b = blockIdx.x * 64 + threadIdx.x;   // 0..511

    float w00 = W_hh[0], w01 = W_hh[1], w02 = W_hh[2];
    float w10 = W_hh[3], w11 = W_hh[4], w12 = W_hh[5];
    float w20 = W_hh[6], w21 = W_hh[7], w22 = W_hh[8];
    float s0v = signal[0], s1v = signal[1], s2v = signal[2];

    float h0 = 0.f, h1 = 0.f, h2 = 0.f;

    const float4* xg = (const float4*)xpk;   // row r: xg[2r] = xp, xg[2r+1] = g

    // Rotating register pipeline (compile-time indices only -> stays in VGPRs).
    float4 bufx[U_PF], bufg[U_PF];
#pragma unroll
    for (int i = 0; i < U_PF; ++i) {
        size_t r = (size_t)i * B_DIM + b;
        bufx[i] = xg[2 * r];
        bufg[i] = xg[2 * r + 1];
    }

#define STEP(sidx, xv, gv)                                                  \
    {                                                                       \
        float a0 = xv.x + w00 * h0 + w01 * h1 + w02 * h2;                   \
        float a1 = xv.y + w10 * h0 + w11 * h1 + w12 * h2;                   \
        float a2 = xv.z + w20 * h0 + w21 * h1 + w22 * h2;                   \
        h0 = tanh_fast(a0);                                                 \
        h1 = tanh_fast(a1);                                                 \
        h2 = tanh_fast(a2);                                                 \
        float l0 = h0 + gv.x, l1 = h1 + gv.y, l2 = h2 + gv.z;               \
        float d = (l2 > l0 && l2 > l1) ? s2v : ((l1 > l0) ? s1v : s0v);     \
        out[(sidx) * B_DIM + b] = d;                                        \
    }

    for (int s0 = 0; s0 < S_DIM - U_PF; s0 += U_PF) {
#pragma unroll
        for (int i = 0; i < U_PF; ++i) {
            float4 xv = bufx[i];
            float4 gv = bufg[i];
            size_t r = (size_t)(s0 + i + U_PF) * B_DIM + b;   // prefetch
            bufx[i] = xg[2 * r];
            bufg[i] = xg[2 * r + 1];
            STEP(s0 + i, xv, gv)
        }
    }
    // Epilogue: last U_PF steps, no prefetch.
#pragma unroll
    for (int i = 0; i < U_PF; ++i) {
        float4 xv = bufx[i];
        float4 gv = bufg[i];
        STEP(S_DIM - U_PF + i, xv, gv)
    }
#undef STEP

    float* hid = out + (size_t)S_DIM * B_DIM + (size_t)b * 3;
    hid[0] = h0; hid[1] = h1; hid[2] = h2;
}

extern "C" void kernel_launch(void* const* d_in, const int* in_sizes, int n_in,
                              void* d_out, int out_size, void* d_ws, size_t ws_size,
                              hipStream_t stream) {
    const float* x      = (const float*)d_in[0];
    const float* gumbel = (const float*)d_in[1];
    const float* W_ih   = (const float*)d_in[2];
    const float* W_hh   = (const float*)d_in[3];
    const float* b_ih   = (const float*)d_in[4];
    const float* b_hh   = (const float*)d_in[5];
    const float* signal = (const float*)d_in[6];

    float* xpk = (float*)d_ws;                    // S*B*8 floats = 16 MB
    float* out = (float*)d_out;

    // 32 lanes per row -> S*B*32 threads.
    k_inproj<<<(S_DIM * B_DIM * 32) / 256, 256, 0, stream>>>(
        x, gumbel, W_ih, b_ih, b_hh, xpk);
    k_scan<<<B_DIM / 64, 64, 0, stream>>>(xpk, W_hh, signal, out);
}